// Round 23
// baseline (215.355 us; speedup 1.0000x reference)
//
#include <hip/hip_runtime.h>
#include <hip/hip_bf16.h>
#include <stdint.h>

// ROUND 23 = r22 (188.5 us) + ONE change: __launch_bounds__(256, 4) on main
// (force <=128 VGPR -> 4 blocks/CU instead of est. 3). Everything else
// byte-identical to r22.
#define NNZ       34473347LL
#define IDX0_OFF  4202432LL
#define IDX1_OFF  38675779LL
#define VALS_OFF  73149126LL
#define OUT_TOTAL 107622473LL

typedef float f4a __attribute__((ext_vector_type(4), aligned(4)));

__constant__ int       cN[9] = {0, 65663, 32831, 16415, 8207, 4103, 2051, 1025, 512};
__constant__ long long cV[9] = {0, 34473347LL, 17171011LL, 8552675LL, 4259923LL,
                                2121755LL, 1056775LL, 526337LL, 262144LL};
__constant__ int       cSZ[8] = {0, 131325, 65661, 32829, 16413, 8205, 4101, 2049};
__constant__ int gD[21] = {2, 3,3, 4,4,4, 5,5,5,5, 6,6,6,6,6, 7,7,7,7,7,7};
__constant__ int gA[21] = {1, 1,2, 1,2,3, 1,2,3,4, 1,2,3,4,5, 1,2,3,4,5,6};
__constant__ int gB[21] = {0, 2,6, 10,18,26, 34,50,66,82, 98,130,162,194,226,
                           258,322,386,450,514,578};

// main-kernel role layout: leaf [0,2048) | int [2048,2304) | idx_int
// [2304,5902) | nodeL [5902,9998) | mp [9998,10191)
#define MB_LEAF  2048
#define MB_INT   2304
#define MB_IDXI  5902
#define MB_NODEL 9998
#define MB_ALL   10191

// ---- stage 1: per-leaf feature sums (ws) ----
__global__ void r23_sums(const float* __restrict__ X, float* __restrict__ sums) {
    __shared__ float part[4][64];
    int t = blockIdx.x;
    int k = threadIdx.x & 63, p = threadIdx.x >> 6;
    const float* xp = X + (long long)t * 32768;
    float s = 0.f;
    for (int i = p * 128; i < p * 128 + 128; ++i) s += xp[(long long)i * 64 + k];
    part[p][k] = s;
    __syncthreads();
    if (threadIdx.x < 64)
        sums[t * 64 + k] = part[0][k] + part[1][k] + part[2][k] + part[3][k];
}

// ---- stage 2: ALL means in parallel (range-mean identity) ----
__global__ void r23_means(const float* __restrict__ sums, float* __restrict__ means,
                          float* __restrict__ mn2, float* __restrict__ out) {
    int h = blockIdx.x + 1;
    int k = threadIdx.x;
    int d = 32 - __clz(h);
    int t = h - (1 << (d - 1));
    int lo = t << (8 - d), cnt = 1 << (8 - d);
    float s = 0.f;
    for (int l = lo; l < lo + cnt; ++l) s += sums[l * 64 + k];
    float mv = s / (float)(1 << (17 - d));
    means[blockIdx.x * 64 + k] = mv;
    long long bb = 0;
    for (int jj = 1; jj <= d - 1; ++jj)
        if ((t >> (d - 1 - jj)) & 1) bb += cN[jj + 1];
    out[(bb + cN[d] - 1) * 64 + k] = mv;
    float sq = mv * mv;
    #pragma unroll
    for (int o = 32; o; o >>= 1) sq += __shfl_xor(sq, o, 64);
    if (k == 0) mn2[blockIdx.x] = sq;
}

// ---- stage 3: MAIN fused kernel: leaf | int | idx_int | nodeL | meanpairs ----
__global__ __launch_bounds__(256, 4) void r23_main(const float* __restrict__ X,
                                                   const float* __restrict__ means,
                                                   const float* __restrict__ mn2,
                                                   float* __restrict__ out) {
    __shared__ float As[32][128];
    __shared__ float Bs[32][128];
    int bid = blockIdx.x;
    int tid = threadIdx.x;

    if (bid < MB_LEAF) {
        // ---------------- leaf tiles: vals + idx0 + idx1 ----------------
        int t = bid >> 4, tile = bid & 15, br = tile >> 2, bc = tile & 3;
        long long voff = 0; int nb = 0;
        #pragma unroll
        for (int jj = 1; jj <= 7; ++jj)
            if ((t >> (7 - jj)) & 1) { voff += cV[jj + 1]; nb += cN[jj + 1]; }
        const float* xleaf = X + (long long)t * 32768;

        float acc[8][8] = {};
        float na[8] = {}, nb2[8] = {};
        for (int ks = 0; ks < 64; ks += 32) {
            __syncthreads();
            #pragma unroll
            for (int u = 0; u < 4; ++u) {
                int idx = tid * 4 + u;
                int i = idx >> 3, k4 = (idx & 7) * 4;
                float4 va = *(const float4*)&xleaf[(long long)(br * 128 + i) * 64 + ks + k4];
                As[k4 + 0][i] = va.x; As[k4 + 1][i] = va.y; As[k4 + 2][i] = va.z; As[k4 + 3][i] = va.w;
                float4 vb = *(const float4*)&xleaf[(long long)(bc * 128 + i) * 64 + ks + k4];
                Bs[k4 + 0][i] = vb.x; Bs[k4 + 1][i] = vb.y; Bs[k4 + 2][i] = vb.z; Bs[k4 + 3][i] = vb.w;
            }
            __syncthreads();
            int ty = tid >> 4, tx = tid & 15;
            for (int k = 0; k < 32; ++k) {
                float a[8], bb[8];
                *(float4*)&a[0]  = *(const float4*)&As[k][ty * 8];
                *(float4*)&a[4]  = *(const float4*)&As[k][ty * 8 + 4];
                *(float4*)&bb[0] = *(const float4*)&Bs[k][tx * 4];
                *(float4*)&bb[4] = *(const float4*)&Bs[k][64 + tx * 4];
                #pragma unroll
                for (int r = 0; r < 8; ++r)
                    #pragma unroll
                    for (int c = 0; c < 8; ++c) acc[r][c] += a[r] * bb[c];
                #pragma unroll
                for (int r = 0; r < 8; ++r) na[r] = fmaf(a[r], a[r], na[r]);
                #pragma unroll
                for (int c = 0; c < 8; ++c) nb2[c] = fmaf(bb[c], bb[c], nb2[c]);
            }
        }

        int ty = tid >> 4, tx = tid & 15;
        int r0g = br * 128 + ty * 8;
        int cga = bc * 128 + tx * 4;

        f4a i1q[2];
        #pragma unroll
        for (int c = 0; c < 4; ++c) {
            i1q[0][c] = (float)(nb + cga + c);
            i1q[1][c] = (float)(nb + cga + 64 + c);
        }

        #pragma unroll
        for (int r = 0; r < 8; ++r) {
            int grow = r0g + r;
            float nar = na[r];
            float i0f = (float)(nb + grow);
            f4a i0q = {i0f, i0f, i0f, i0f};
            long long rb = voff + (long long)grow * 512;
            #pragma unroll
            for (int h = 0; h < 2; ++h) {
                long long cb = rb + cga + h * 64;
                f4a vv;
                #pragma unroll
                for (int c = 0; c < 4; ++c) {
                    float d2 = nar + nb2[h * 4 + c] - 2.0f * acc[r][h * 4 + c];
                    vv[c] = __expf(-d2 * 0.015625f);
                }
                *(f4a*)&out[VALS_OFF + cb] = vv;
                *(f4a*)&out[IDX0_OFF + cb] = i0q;
                *(f4a*)&out[IDX1_OFF + cb] = i1q[h];
            }
        }
    } else if (bid < MB_INT) {
        // ---- internal-chunk X-row values: one THREAD per row ----
        int r = ((bid - MB_LEAF) << 8) + tid;
        float4 xv[16];
        const float4* xp = (const float4*)(X + (long long)r * 64);
        #pragma unroll
        for (int i = 0; i < 16; ++i) xv[i] = xp[i];
        float xnr = 0.f;
        #pragma unroll
        for (int i = 0; i < 16; ++i)
            xnr += xv[i].x * xv[i].x + xv[i].y * xv[i].y
                 + xv[i].z * xv[i].z + xv[i].w * xv[i].w;
        int t7 = r >> 9, col = r & 511;
        long long voff = 0;
        #pragma unroll
        for (int d = 1; d <= 7; ++d) {
            int h0 = (1 << (d - 1)) + (r >> (17 - d)) - 1;   // wave-uniform
            const float* mrow = means + h0 * 64;
            float dot = 0.f;
            #pragma unroll
            for (int i = 0; i < 16; ++i)
                dot += xv[i].x * mrow[4 * i] + xv[i].y * mrow[4 * i + 1]
                     + xv[i].z * mrow[4 * i + 2] + xv[i].w * mrow[4 * i + 3];
            long long q = col;
            #pragma unroll
            for (int jj = 1; jj <= 7; ++jj)
                if (jj >= d && ((t7 >> (7 - jj)) & 1)) q += cN[jj + 1];
            long long m = cN[d] - 1;
            long long co = voff + 2 * cV[d + 1];
            float v = __expf(-(xnr - 2.0f * dot + mn2[h0]) * 0.015625f);
            out[VALS_OFF + co + q]     = v;
            out[VALS_OFF + co + m + q] = v;
            if ((t7 >> (7 - d)) & 1) voff += cV[d + 1];
        }
    } else if (bid < MB_IDXI) {
        // ---- internal-chunk indices ----
        int local = bid - MB_INT;
        int d = local / 514 + 1;
        int bx = local % 514;
        int sz = cSZ[d];
        int m = cN[d] - 1;
        long long pos = (long long)bx * 256 + tid;
        long long tot = (long long)(1 << (d - 1)) * sz;
        if (pos < tot) {
            int t = (int)(pos / sz);
            int e = (int)(pos % sz);
            long long voff = 0; long long base = 0;
            for (int jj = 1; jj < d; ++jj)
                if ((t >> (d - 1 - jj)) & 1) { voff += cV[jj + 1]; base += cN[jj + 1]; }
            long long p = voff + 2 * cV[d + 1] + e;
            long long i0, i1;
            if (e < m)          { i0 = base + e;     i1 = base + m; }
            else if (e < 2 * m) { i0 = base + m;     i1 = base + e - m; }
            else                { i0 = base + m;     i1 = base + m; }
            out[IDX0_OFF + p] = (float)i0;
            out[IDX1_OFF + p] = (float)i1;
        }
    } else if (bid < MB_NODEL) {
        // ---- leaf-node rows ----
        int local = bid - MB_IDXI;
        long long e = ((long long)local * 256 + tid) * 4;
        int t = (int)(e >> 15);
        int l = (int)(e & 32767);
        int j = l >> 6, k = l & 63;
        int b = 0;
        #pragma unroll
        for (int jj = 1; jj <= 7; ++jj) if ((t >> (7 - jj)) & 1) b += cN[jj + 1];
        float4 v = *(const float4*)&X[e];
        *(float4*)&out[((long long)b + j) * 64 + k] = v;
    } else {
        // ---- mean-vs-mean pairs + 1.0 entries ----
        int local = bid - MB_NODEL;
        int wv = (local << 2) + (tid >> 6);
        int lane = tid & 63;
        if (wv >= 769) return;
        if (wv < 642) {
            int g = 0;
            while (g < 20 && wv >= gB[g + 1]) ++g;
            int dp = gD[g], a = gA[g];
            int tp = wv - gB[g];
            int hp = (1 << (dp - 1)) + tp;
            int ha = hp >> (dp - a);
            float da = means[(hp - 1) * 64 + lane] - means[(ha - 1) * 64 + lane];
            float s = da * da;
            #pragma unroll
            for (int o = 32; o; o >>= 1) s += __shfl_xor(s, o, 64);
            if (lane == 0) {
                float v = __expf(-s * 0.015625f);
                int ta = ha - (1 << (a - 1));
                long long voff = 0;
                for (int jj = 1; jj <= a - 1; ++jj)
                    if ((ta >> (a - 1 - jj)) & 1) voff += cV[jj + 1];
                long long q = cN[dp] - 1;
                for (int jj = a; jj <= dp - 1; ++jj)
                    if ((tp >> (dp - 1 - jj)) & 1) q += cN[jj + 1];
                long long m = cN[a] - 1;
                long long co = voff + 2 * cV[a + 1];
                out[VALS_OFF + co + q]     = v;
                out[VALS_OFF + co + m + q] = v;
            }
        } else if (lane == 0) {
            int h = wv - 642 + 1;
            int d = 32 - __clz(h);
            int t = h - (1 << (d - 1));
            long long voff = 0;
            for (int jj = 1; jj <= d - 1; ++jj)
                if ((t >> (d - 1 - jj)) & 1) voff += cV[jj + 1];
            long long m = cN[d] - 1;
            out[VALS_OFF + voff + 2 * cV[d + 1] + 2 * m] = 1.0f;
        }
    }
}

extern "C" void kernel_launch(void* const* d_in, const int* in_sizes, int n_in,
                              void* d_out, int out_size, void* d_ws, size_t ws_size,
                              hipStream_t stream) {
    const float* X = (const float*)d_in[0];
    float* out = (float*)d_out;

    float* sums  = (float*)d_ws;              // 128*64
    float* means = sums + 128 * 64;           // 127*64
    float* mn2   = means + 127 * 64;          // 127

    if (out_size != (int)OUT_TOTAL) return;
    if (ws_size < (size_t)(128 * 64 + 127 * 64 + 128) * sizeof(float)) return;

    r23_sums <<<128,    256, 0, stream>>>(X, sums);
    r23_means<<<127,     64, 0, stream>>>(sums, means, mn2, out);
    r23_main <<<MB_ALL, 256, 0, stream>>>(X, means, mn2, out);
}